// Round 2
// baseline (117.004 us; speedup 1.0000x reference)
//
#include <hip/hip_runtime.h>

// Mutual information, N=8 images of 384x384, 50 soft bins.
// Kernel 1: fused soft-bin + batched 64x64 (padded from 50) MFMA GEMM over K=D.
// Kernel 2: single-block finalize (total, marginals, MI log-sum).
//
// Math: xs[b] = t_b - t_{b+1}, t_j = sigmoid(10v - 0.2j) = 1/(1 + e^{0.2j} e^{-10v}).
// One exp per element, 51 rcp. Values scaled x256 before f16 (avoids f16 denormals);
// scale cancels exactly in p = h / sum(h).
//
// R1 resubmission: previous round failed on container acquisition (infra), not
// kernel evidence — source unchanged.

#define D_TOTAL   147456
#define NBATCH    8
#define BINS      50
#define KSLICES   64                       // blocks per image (split-K)
#define KC        128                      // d-columns per block iteration
#define SLICE_LEN (D_TOTAL / KSLICES)      // 2304
#define ITERS     (SLICE_LEN / KC)         // 18
#define LDS_STR   136                      // 128 + 8 f16 pad (272 B rows, 16B-aligned, bank-spread)

typedef _Float16 half8 __attribute__((ext_vector_type(8)));
typedef float    f32x4 __attribute__((ext_vector_type(4)));

struct Tab { float c[BINS + 1]; };
constexpr Tab make_tab() {
    Tab t{};
    double c = 1.0;
    const double lam = 1.2214027581601699;  // e^0.2
    for (int i = 0; i <= BINS; ++i) { t.c[i] = (float)c; c *= lam; }
    return t;
}
constexpr Tab TAB = make_tab();

__global__ __launch_bounds__(256) void hgram_kernel(const float* __restrict__ im1,
                                                    const float* __restrict__ im2,
                                                    float* __restrict__ hg) {
    __shared__ __align__(16) _Float16 Xs[64][LDS_STR];
    __shared__ __align__(16) _Float16 Ys[64][LDS_STR];

    const int tid   = threadIdx.x;
    const int blk   = blockIdx.x;
    const int n     = blk >> 6;       // 64 slices per image
    const int slice = blk & 63;
    const int base  = n * D_TOTAL + slice * SLICE_LEN;

    // Zero LDS once (rows 50..63 stay zero; staging only rewrites rows 0..49).
    {
        unsigned* px = (unsigned*)&Xs[0][0];
        unsigned* py = (unsigned*)&Ys[0][0];
        for (int i = tid; i < 64 * LDS_STR / 2; i += 256) { px[i] = 0u; py[i] = 0u; }
    }
    __syncthreads();

    const int col = tid & 127;        // d-column within tile
    const int isY = tid >> 7;         // threads 0..127 stage X, 128..255 stage Y
    const float*  src = isY ? im2 : im1;
    _Float16*     dst = isY ? &Ys[0][0] : &Xs[0][0];

    const int lane = tid & 63;
    const int w    = tid >> 6;                 // wave id: rows [16w, 16w+16)
    const int arow = (w << 4) + (lane & 15);   // A-frag row
    const int brow = lane & 15;                // B-frag col (row of Ys)
    const int kg   = (lane >> 4) << 3;         // k sub-group offset (0,8,16,24)

    f32x4 acc0 = {0.f, 0.f, 0.f, 0.f};
    f32x4 acc1 = acc0, acc2 = acc0, acc3 = acc0;

    for (int it = 0; it < ITERS; ++it) {
        // ---- stage: one element -> 50 soft-bin weights (x256, f16) into LDS column ----
        {
            float v = src[base + it * KC + col];
            float E = __builtin_amdgcn_exp2f(v * -14.426950408889634f);   // e^{-10v}
            // t'_j = 256/(1 + c_j E) via rcp(fma(u, 1/256, 1/256))
            float tprev = __builtin_amdgcn_rcpf(__builtin_fmaf(E, 0.00390625f, 0.00390625f));
            #pragma unroll
            for (int b = 0; b < BINS; ++b) {
                float u = TAB.c[b + 1] * E;   // compile-time literal * E
                float t = __builtin_amdgcn_rcpf(__builtin_fmaf(u, 0.00390625f, 0.00390625f));
                dst[b * LDS_STR + col] = (_Float16)(tprev - t);
                tprev = t;
            }
        }
        __syncthreads();
        // ---- MFMA: this wave's 16 rows x all 64 cols, K = 128 ----
        #pragma unroll
        for (int ks = 0; ks < 4; ++ks) {
            const int k0 = ks * 32 + kg;
            half8 a  = *(const half8*)&Xs[arow][k0];
            half8 b0 = *(const half8*)&Ys[brow][k0];
            half8 b1 = *(const half8*)&Ys[16 + brow][k0];
            half8 b2 = *(const half8*)&Ys[32 + brow][k0];
            half8 b3 = *(const half8*)&Ys[48 + brow][k0];
            acc0 = __builtin_amdgcn_mfma_f32_16x16x32_f16(a, b0, acc0, 0, 0, 0);
            acc1 = __builtin_amdgcn_mfma_f32_16x16x32_f16(a, b1, acc1, 0, 0, 0);
            acc2 = __builtin_amdgcn_mfma_f32_16x16x32_f16(a, b2, acc2, 0, 0, 0);
            acc3 = __builtin_amdgcn_mfma_f32_16x16x32_f16(a, b3, acc3, 0, 0, 0);
        }
        __syncthreads();
    }

    // ---- epilogue: atomic-add the real 50x50 region into hg[n][64][64] ----
    float* hgn = hg + n * 4096;
    const int ccol = lane & 15;
    const int rbase = (w << 4) + ((lane >> 4) << 2);
    #pragma unroll
    for (int c = 0; c < 4; ++c) {
        f32x4 a = (c == 0) ? acc0 : (c == 1) ? acc1 : (c == 2) ? acc2 : acc3;
        const int colc = c * 16 + ccol;
        if (colc < BINS) {
            #pragma unroll
            for (int r = 0; r < 4; ++r) {
                const int row = rbase + r;
                if (row < BINS) atomicAdd(&hgn[row * 64 + colc], a[r]);
            }
        }
    }
}

__global__ __launch_bounds__(1024) void finalize_kernel(const float* __restrict__ hg,
                                                        float* __restrict__ out) {
    __shared__ float red[16];
    __shared__ float marg[2][NBATCH][64];   // [0]=row sums (mx), [1]=col sums (my)
    __shared__ float sT;
    const int tid = threadIdx.x;

    // phase 1: grand total
    float s = 0.f;
    for (int i = tid; i < NBATCH * 4096; i += 1024) s += hg[i];
    #pragma unroll
    for (int o = 32; o > 0; o >>= 1) s += __shfl_down(s, o, 64);
    if ((tid & 63) == 0) red[tid >> 6] = s;
    __syncthreads();
    if (tid == 0) {
        float t = 0.f;
        for (int i = 0; i < 16; ++i) t += red[i];
        sT = t;
    }

    // phase 2: marginals — exactly 1024 tasks (8 n x 64 idx x {row,col})
    {
        const int n = tid >> 7;
        const int rem = tid & 127;
        const int which = rem >> 6;
        const int j = rem & 63;
        const float* b = hg + n * 4096;
        float m = 0.f;
        if (which == 0) { for (int c2 = 0; c2 < 64; ++c2) m += b[j * 64 + c2]; }
        else            { for (int b2 = 0; b2 < 64; ++b2) m += b[b2 * 64 + j]; }
        marg[which][n][j] = m;
    }
    __syncthreads();

    // phase 3: MI = sum p * (log(p+eps) - log(mx*my+eps)); padded entries contribute 0.
    const float invT = 1.0f / sT;
    float mi = 0.f;
    for (int i = tid; i < NBATCH * 4096; i += 1024) {
        const int n = i >> 12;
        const int rc = i & 4095;
        const int b = rc >> 6, c = rc & 63;
        const float p  = hg[i] * invT;
        const float jo = (marg[0][n][b] * invT) * (marg[1][n][c] * invT);
        mi += p * (__logf(p + 1e-8f) - __logf(jo + 1e-8f));
    }
    #pragma unroll
    for (int o = 32; o > 0; o >>= 1) mi += __shfl_down(mi, o, 64);
    if ((tid & 63) == 0) red[tid >> 6] = mi;
    __syncthreads();
    if (tid == 0) {
        float t = 0.f;
        for (int i = 0; i < 16; ++i) t += red[i];
        out[0] = t;
    }
}

extern "C" void kernel_launch(void* const* d_in, const int* in_sizes, int n_in,
                              void* d_out, int out_size, void* d_ws, size_t ws_size,
                              hipStream_t stream) {
    const float* im1 = (const float*)d_in[0];
    const float* im2 = (const float*)d_in[1];
    float* out = (float*)d_out;
    float* hg  = (float*)d_ws;   // [8][64][64] f32 = 131072 B of workspace

    hipMemsetAsync(d_ws, 0, NBATCH * 4096 * sizeof(float), stream);
    hgram_kernel<<<dim3(NBATCH * KSLICES), dim3(256), 0, stream>>>(im1, im2, hg);
    finalize_kernel<<<dim3(1), dim3(1024), 0, stream>>>(hg, out);
}

// Round 3
// 113.422 us; speedup vs baseline: 1.0316x; 1.0316x over previous
//
#include <hip/hip_runtime.h>

// Mutual information, N=8 images of 384x384, 50 soft bins.
// Kernel 1: fused soft-bin + batched 64x64 (padded from 50) MFMA GEMM over K=D.
// Kernel 2: single-block finalize (total, marginals, MI log-sum).
//
// Math: xs[b] = t_b - t_{b+1}, t_j = sigmoid(10v - 0.2j) = 1/(1 + e^{0.2j} e^{-10v}).
// One exp per element, 51 rcp. Values scaled x256 before f16 (avoids f16 denormals);
// scale cancels exactly in p = h / sum(h).
//
// R3: (a) KSLICES 64->128: grid 1024 = 4 blocks/CU (was grid-limited to 2),
//     16 waves/CU to hide the 2-barriers-per-iter drain.
//     (b) LDS_STR 136->152 f16: row stride 76 dwords === 12 (mod 32); b128 frag
//     reads tile all 8 aligned 4-dword blocks exactly 8x across 64 lanes
//     (stride===4 mod 32 piled 8 lanes per block -> 2.95M SQ_LDS_BANK_CONFLICT).

#define D_TOTAL   147456
#define NBATCH    8
#define BINS      50
#define KSLICES   128                      // blocks per image (split-K)
#define KC        128                      // d-columns per block iteration
#define SLICE_LEN (D_TOTAL / KSLICES)      // 1152
#define ITERS     (SLICE_LEN / KC)         // 9
#define LDS_STR   152                      // 128 + 24 f16 pad: 76 dwords = 12 mod 32

typedef _Float16 half8 __attribute__((ext_vector_type(8)));
typedef float    f32x4 __attribute__((ext_vector_type(4)));

struct Tab { float c[BINS + 1]; };
constexpr Tab make_tab() {
    Tab t{};
    double c = 1.0;
    const double lam = 1.2214027581601699;  // e^0.2
    for (int i = 0; i <= BINS; ++i) { t.c[i] = (float)c; c *= lam; }
    return t;
}
constexpr Tab TAB = make_tab();

__global__ __launch_bounds__(256, 4) void hgram_kernel(const float* __restrict__ im1,
                                                       const float* __restrict__ im2,
                                                       float* __restrict__ hg) {
    __shared__ __align__(16) _Float16 Xs[64][LDS_STR];
    __shared__ __align__(16) _Float16 Ys[64][LDS_STR];

    const int tid   = threadIdx.x;
    const int blk   = blockIdx.x;
    const int n     = blk >> 7;       // 128 slices per image
    const int slice = blk & 127;
    const int base  = n * D_TOTAL + slice * SLICE_LEN;

    // Zero LDS once (rows 50..63 stay zero; staging only rewrites rows 0..49).
    {
        unsigned* px = (unsigned*)&Xs[0][0];
        unsigned* py = (unsigned*)&Ys[0][0];
        for (int i = tid; i < 64 * LDS_STR / 2; i += 256) { px[i] = 0u; py[i] = 0u; }
    }
    __syncthreads();

    const int col = tid & 127;        // d-column within tile
    const int isY = tid >> 7;         // threads 0..127 stage X, 128..255 stage Y
    const float*  src = isY ? im2 : im1;
    _Float16*     dst = isY ? &Ys[0][0] : &Xs[0][0];

    const int lane = tid & 63;
    const int w    = tid >> 6;                 // wave id: rows [16w, 16w+16)
    const int arow = (w << 4) + (lane & 15);   // A-frag row
    const int brow = lane & 15;                // B-frag col (row of Ys)
    const int kg   = (lane >> 4) << 3;         // k sub-group offset (0,8,16,24)

    f32x4 acc0 = {0.f, 0.f, 0.f, 0.f};
    f32x4 acc1 = acc0, acc2 = acc0, acc3 = acc0;

    for (int it = 0; it < ITERS; ++it) {
        // ---- stage: one element -> 50 soft-bin weights (x256, f16) into LDS column ----
        {
            float v = src[base + it * KC + col];
            float E = __builtin_amdgcn_exp2f(v * -14.426950408889634f);   // e^{-10v}
            // t'_j = 256/(1 + c_j E) via rcp(fma(u, 1/256, 1/256))
            float tprev = __builtin_amdgcn_rcpf(__builtin_fmaf(E, 0.00390625f, 0.00390625f));
            #pragma unroll
            for (int b = 0; b < BINS; ++b) {
                float u = TAB.c[b + 1] * E;   // compile-time literal * E
                float t = __builtin_amdgcn_rcpf(__builtin_fmaf(u, 0.00390625f, 0.00390625f));
                dst[b * LDS_STR + col] = (_Float16)(tprev - t);
                tprev = t;
            }
        }
        __syncthreads();
        // ---- MFMA: this wave's 16 rows x all 64 cols, K = 128 ----
        #pragma unroll
        for (int ks = 0; ks < 4; ++ks) {
            const int k0 = ks * 32 + kg;
            half8 a  = *(const half8*)&Xs[arow][k0];
            half8 b0 = *(const half8*)&Ys[brow][k0];
            half8 b1 = *(const half8*)&Ys[16 + brow][k0];
            half8 b2 = *(const half8*)&Ys[32 + brow][k0];
            half8 b3 = *(const half8*)&Ys[48 + brow][k0];
            acc0 = __builtin_amdgcn_mfma_f32_16x16x32_f16(a, b0, acc0, 0, 0, 0);
            acc1 = __builtin_amdgcn_mfma_f32_16x16x32_f16(a, b1, acc1, 0, 0, 0);
            acc2 = __builtin_amdgcn_mfma_f32_16x16x32_f16(a, b2, acc2, 0, 0, 0);
            acc3 = __builtin_amdgcn_mfma_f32_16x16x32_f16(a, b3, acc3, 0, 0, 0);
        }
        __syncthreads();
    }

    // ---- epilogue: atomic-add the real 50x50 region into hg[n][64][64] ----
    float* hgn = hg + n * 4096;
    const int ccol = lane & 15;
    const int rbase = (w << 4) + ((lane >> 4) << 2);
    #pragma unroll
    for (int c = 0; c < 4; ++c) {
        f32x4 a = (c == 0) ? acc0 : (c == 1) ? acc1 : (c == 2) ? acc2 : acc3;
        const int colc = c * 16 + ccol;
        if (colc < BINS) {
            #pragma unroll
            for (int r = 0; r < 4; ++r) {
                const int row = rbase + r;
                if (row < BINS) atomicAdd(&hgn[row * 64 + colc], a[r]);
            }
        }
    }
}

__global__ __launch_bounds__(1024) void finalize_kernel(const float* __restrict__ hg,
                                                        float* __restrict__ out) {
    __shared__ float red[16];
    __shared__ float marg[2][NBATCH][64];   // [0]=row sums (mx), [1]=col sums (my)
    __shared__ float sT;
    const int tid = threadIdx.x;

    // phase 1: grand total
    float s = 0.f;
    for (int i = tid; i < NBATCH * 4096; i += 1024) s += hg[i];
    #pragma unroll
    for (int o = 32; o > 0; o >>= 1) s += __shfl_down(s, o, 64);
    if ((tid & 63) == 0) red[tid >> 6] = s;
    __syncthreads();
    if (tid == 0) {
        float t = 0.f;
        for (int i = 0; i < 16; ++i) t += red[i];
        sT = t;
    }

    // phase 2: marginals — exactly 1024 tasks (8 n x 64 idx x {row,col})
    {
        const int n = tid >> 7;
        const int rem = tid & 127;
        const int which = rem >> 6;
        const int j = rem & 63;
        const float* b = hg + n * 4096;
        float m = 0.f;
        if (which == 0) { for (int c2 = 0; c2 < 64; ++c2) m += b[j * 64 + c2]; }
        else            { for (int b2 = 0; b2 < 64; ++b2) m += b[b2 * 64 + j]; }
        marg[which][n][j] = m;
    }
    __syncthreads();

    // phase 3: MI = sum p * (log(p+eps) - log(mx*my+eps)); padded entries contribute 0.
    const float invT = 1.0f / sT;
    float mi = 0.f;
    for (int i = tid; i < NBATCH * 4096; i += 1024) {
        const int n = i >> 12;
        const int rc = i & 4095;
        const int b = rc >> 6, c = rc & 63;
        const float p  = hg[i] * invT;
        const float jo = (marg[0][n][b] * invT) * (marg[1][n][c] * invT);
        mi += p * (__logf(p + 1e-8f) - __logf(jo + 1e-8f));
    }
    #pragma unroll
    for (int o = 32; o > 0; o >>= 1) mi += __shfl_down(mi, o, 64);
    if ((tid & 63) == 0) red[tid >> 6] = mi;
    __syncthreads();
    if (tid == 0) {
        float t = 0.f;
        for (int i = 0; i < 16; ++i) t += red[i];
        out[0] = t;
    }
}

extern "C" void kernel_launch(void* const* d_in, const int* in_sizes, int n_in,
                              void* d_out, int out_size, void* d_ws, size_t ws_size,
                              hipStream_t stream) {
    const float* im1 = (const float*)d_in[0];
    const float* im2 = (const float*)d_in[1];
    float* out = (float*)d_out;
    float* hg  = (float*)d_ws;   // [8][64][64] f32 = 131072 B of workspace

    hipMemsetAsync(d_ws, 0, NBATCH * 4096 * sizeof(float), stream);
    hgram_kernel<<<dim3(NBATCH * KSLICES), dim3(256), 0, stream>>>(im1, im2, hg);
    finalize_kernel<<<dim3(1), dim3(1024), 0, stream>>>(hg, out);
}